// Round 16
// baseline (22.660 us; speedup 1.0000x reference)
//
#include <hip/hip_runtime.h>
#include <math.h>

// NUFFT forward via separable phase + bf16 MFMA. No workspace.
// ksp[c,k] = sum_x Ex[k,x] * ( sum_y img[c,x,y] * Ey[k,y] )
// R16 = R15 structure (2-coil slab, 4 k-quarter waves, LDS dbuf, 1 barrier/
// iter, proven swizzle) with sincos work cut ~4-5x via phase RECURRENCE:
// R14==R15 (21.4us) under 2x occupancy proved a per-CU VALU throughput
// bound == __sincosf (stage C recomputed Ex 8x redundantly: 8.4M pairs).
// Now: Ex per lane = base+step sincos once, then 1 complex mult per iter;
// Ey table rows walk p by complex mult (2 sincos + 16 cmul per thread).

#define K_TOTAL 8192
#define KB      64          // k's per block (4 quarters of 16)
#define NX      128
#define NY      128
#define EY_LD   136         // bf16 row stride (pad +8)

typedef short  bf16x8 __attribute__((ext_vector_type(8)));
typedef float  f32x4  __attribute__((ext_vector_type(4)));

__device__ inline unsigned short f32_to_bf16_rne(float f) {
    unsigned int u = __float_as_uint(f);
    u += 0x7FFFu + ((u >> 16) & 1u);
    return (unsigned short)(u >> 16);
}
__device__ inline unsigned pack2(float a, float b) {
    return (unsigned)f32_to_bf16_rne(a) | ((unsigned)f32_to_bf16_rne(b) << 16);
}

__global__ __launch_bounds__(512, 2) void nufft_mfma_kernel(
    const float* __restrict__ imgR,
    const float* __restrict__ imgI,
    const float* __restrict__ trj,
    float* __restrict__ out)
{
    __shared__ __align__(16) unsigned short eyR[KB][EY_LD];
    __shared__ __align__(16) unsigned short eyI[KB][EY_LD];
    // double-buffered slabs: [buf][coil2][RI][16 rows * 128 y] bf16, swizzled
    __shared__ __align__(16) unsigned short slab[2][2][2][16 * 128];

    const int tid = threadIdx.x;
    const int bid = blockIdx.x;
    const int cg  = bid >> 7;          // coil pair: 0..3 -> coils 2cg,2cg+1
    const int kg0 = (bid & 127) * KB;  // base k of this block

    // ---- Phase A: Ey table via recurrence: thread = (row kk, 16-seg p0) ----
    {
        const int kk = tid >> 3;          // 0..63
        const int p0 = (tid & 7) * 16;    // 0,16,...,112
        const float ky = trj[(kg0 + kk) * 2 + 1];

        float t0 = -ky * (float)(p0 - 64) * (1.0f / 128.0f);
        t0 -= floorf(t0);
        float s_, c_; __sincosf(6.283185307179586f * t0, &s_, &c_);

        float ts = -ky * (1.0f / 128.0f);
        ts -= floorf(ts);
        float ss, sc; __sincosf(6.283185307179586f * ts, &ss, &sc);

#pragma unroll
        for (int m = 0; m < 16; ++m) {
            eyR[kk][p0 + m] = f32_to_bf16_rne(c_);
            eyI[kk][p0 + m] = f32_to_bf16_rne(s_);
            const float cn = c_ * sc - s_ * ss;
            s_ = c_ * ss + s_ * sc;
            c_ = cn;
        }
    }
    __syncthreads();

    const int wave = tid >> 6;      // 0..7
    const int lane = tid & 63;
    const int l15  = lane & 15;
    const int lg   = lane >> 4;     // 0..3
    const int c2   = wave & 1;      // coil within pair (read side)
    const int kq   = wave >> 1;     // k-quarter: 16 k's
    const int c    = cg * 2 + c2;   // this wave's output coil
    const int srow = wave * 2 + (lane >> 5);  // staging row 0..15
    const int seg  = lane & 31;               // float4 segment in row

    // kx preload for stage C: k = kg0 + kq*16 + lg*4 + j
    float kxv[4];
#pragma unroll
    for (int j = 0; j < 4; ++j)
        kxv[j] = trj[(kg0 + kq * 16 + lg * 4 + j) * 2 + 0];

    // Ex state: base at x = l15 (x0=0), step for Δx=16 -> exp(-2πi kx/8)
    float exr[4], exi[4], str_[4], sti[4];
#pragma unroll
    for (int j = 0; j < 4; ++j) {
        float t = -kxv[j] * (float)(l15 - 64) * (1.0f / 128.0f);
        t -= floorf(t);
        __sincosf(6.283185307179586f * t, &exi[j], &exr[j]);
        float u = -kxv[j] * 0.125f;
        u -= floorf(u);
        __sincosf(6.283185307179586f * u, &sti[j], &str_[j]);
    }

    // ---- A-fragment preload: Ey rows kq*16 + l15 (R4-proven layout) ----
    bf16x8 aR[4], aI[4];
#pragma unroll
    for (int ys = 0; ys < 4; ++ys) {
        const int row = kq * 16 + l15;
        const int y   = ys * 32 + lg * 8;
        aR[ys] = *(const bf16x8*)&eyR[row][y];
        aI[ys] = *(const bf16x8*)&eyI[row][y];
    }

    f32x4 outRe = {0,0,0,0};
    f32x4 outIm = {0,0,0,0};

    const int c0 = cg * 2;          // first coil of the pair
    float4 b0R, b0I, b1R, b1I;

    // ---- prologue: tile 0 -> load, cvt, write slab[0] ----
    {
        b0R = *(const float4*)(imgR + ((c0 + 0) * NX + srow) * NY + seg * 4);
        b0I = *(const float4*)(imgI + ((c0 + 0) * NX + srow) * NY + seg * 4);
        b1R = *(const float4*)(imgR + ((c0 + 1) * NX + srow) * NY + seg * 4);
        b1I = *(const float4*)(imgI + ((c0 + 1) * NX + srow) * NY + seg * 4);

        const int off = srow * 256 + ((seg * 8) ^ ((srow & 15) << 4));
        uint2 v;
        v.x = pack2(b0R.x, b0R.y); v.y = pack2(b0R.z, b0R.w);
        *(uint2*)((char*)&slab[0][0][0][0] + off) = v;
        v.x = pack2(b0I.x, b0I.y); v.y = pack2(b0I.z, b0I.w);
        *(uint2*)((char*)&slab[0][0][1][0] + off) = v;
        v.x = pack2(b1R.x, b1R.y); v.y = pack2(b1R.z, b1R.w);
        *(uint2*)((char*)&slab[0][1][0][0] + off) = v;
        v.x = pack2(b1I.x, b1I.y); v.y = pack2(b1I.z, b1I.w);
        *(uint2*)((char*)&slab[0][1][1][0] + off) = v;
    }
    __syncthreads();

    // ---- main loop: 1 barrier/iter; prefetch overlaps MFMA+stageC ----
    for (int nt = 0; nt < 8; ++nt) {
        const int cur = nt & 1;

        // 1. prefetch tile nt+1 into regs (consumed in step 4)
        if (nt < 7) {
            const int xr = (nt + 1) * 16 + srow;
            b0R = *(const float4*)(imgR + ((c0 + 0) * NX + xr) * NY + seg * 4);
            b0I = *(const float4*)(imgI + ((c0 + 0) * NX + xr) * NY + seg * 4);
            b1R = *(const float4*)(imgR + ((c0 + 1) * NX + xr) * NY + seg * 4);
            b1I = *(const float4*)(imgI + ((c0 + 1) * NX + xr) * NY + seg * 4);
        }

        // 2. MFMA from slab[cur] (proven swizzle/layout)
        const char* sbR = (const char*)&slab[cur][c2][0][0];
        const char* sbI = (const char*)&slab[cur][c2][1][0];
        f32x4 P = {0,0,0,0}, Q = {0,0,0,0}, U = {0,0,0,0}, V = {0,0,0,0};
        const int rowb = l15 * 256;
#pragma unroll
        for (int ys = 0; ys < 4; ++ys) {
            const int inb = (lg * 16 + ys * 64) ^ (l15 << 4);
            const bf16x8 bR = *(const bf16x8*)(sbR + rowb + inb);
            const bf16x8 bI = *(const bf16x8*)(sbI + rowb + inb);
            P = __builtin_amdgcn_mfma_f32_16x16x32_bf16(aR[ys], bR, P, 0, 0, 0);
            Q = __builtin_amdgcn_mfma_f32_16x16x32_bf16(aI[ys], bI, Q, 0, 0, 0);
            U = __builtin_amdgcn_mfma_f32_16x16x32_bf16(aR[ys], bI, U, 0, 0, 0);
            V = __builtin_amdgcn_mfma_f32_16x16x32_bf16(aI[ys], bR, V, 0, 0, 0);
        }

        // 3. stage C: Ex from recurrence (no sincos in the loop)
#pragma unroll
        for (int j = 0; j < 4; ++j) {
            const float TR = P[j] - Q[j];
            const float TI = U[j] + V[j];
            outRe[j] += exr[j] * TR - exi[j] * TI;
            outIm[j] += exr[j] * TI + exi[j] * TR;
            const float nr = exr[j] * str_[j] - exi[j] * sti[j];
            exi[j] = exr[j] * sti[j] + exi[j] * str_[j];
            exr[j] = nr;
        }

        // 4. cvt + swizzled ds_write of tile nt+1 into slab[cur^1]
        if (nt < 7) {
            const int off = srow * 256 + ((seg * 8) ^ ((srow & 15) << 4));
            uint2 v;
            v.x = pack2(b0R.x, b0R.y); v.y = pack2(b0R.z, b0R.w);
            *(uint2*)((char*)&slab[cur ^ 1][0][0][0] + off) = v;
            v.x = pack2(b0I.x, b0I.y); v.y = pack2(b0I.z, b0I.w);
            *(uint2*)((char*)&slab[cur ^ 1][0][1][0] + off) = v;
            v.x = pack2(b1R.x, b1R.y); v.y = pack2(b1R.z, b1R.w);
            *(uint2*)((char*)&slab[cur ^ 1][1][0][0] + off) = v;
            v.x = pack2(b1I.x, b1I.y); v.y = pack2(b1I.z, b1I.w);
            *(uint2*)((char*)&slab[cur ^ 1][1][1][0] + off) = v;
        }

        __syncthreads();   // slab[cur^1] visible to all waves next iter
    }

    // ---- reduce over the 16 x-lanes; lanes with l15==0 write ----
#pragma unroll
    for (int j = 0; j < 4; ++j) {
        float r_ = outRe[j];
        float i_ = outIm[j];
#pragma unroll
        for (int m = 1; m < 16; m <<= 1) {
            r_ += __shfl_xor(r_, m, 64);
            i_ += __shfl_xor(i_, m, 64);
        }
        if (l15 == 0) {
            const int kg = kg0 + kq * 16 + lg * 4 + j;
            ((float2*)out)[c * K_TOTAL + kg] = make_float2(r_, i_);
        }
    }
}

extern "C" void kernel_launch(void* const* d_in, const int* in_sizes, int n_in,
                              void* d_out, int out_size, void* d_ws, size_t ws_size,
                              hipStream_t stream) {
    const float* imgR = (const float*)d_in[0];
    const float* imgI = (const float*)d_in[1];
    const float* trj  = (const float*)d_in[2];
    float* out = (float*)d_out;

    hipLaunchKernelGGL(nufft_mfma_kernel, dim3(512), dim3(512), 0, stream,
                       imgR, imgI, trj, out);
}

// Round 17
// 22.398 us; speedup vs baseline: 1.0117x; 1.0117x over previous
//
#include <hip/hip_runtime.h>
#include <math.h>

// NUFFT forward via separable phase + bf16 MFMA. No workspace.
// ksp[c,k] = sum_x Ex[k,x] * ( sum_y img[c,x,y] * Ey[k,y] )
// R17: ONE-SHOT structure. R14==R15==R16 (~21.4us, insensitive to occupancy
// and VALU count) indicts the 8-iteration barrier-locked skeleton (per-iter
// vmcnt/lgkmcnt drain before s_barrier). Now: stage the ENTIRE 2-coil slab
// (128 KB bf16) once -> ONE barrier -> barrier-free compute loop (pure
// ds_read+MFMA+VALU). Ey A-fragments built in registers via phase
// recurrence (no ey LDS table, no Phase A barrier).

#define K_TOTAL 8192
#define KB      64          // k's per block (4 quarters of 16)
#define NX      128
#define NY      128

typedef short  bf16x8 __attribute__((ext_vector_type(8)));
typedef float  f32x4  __attribute__((ext_vector_type(4)));

__device__ inline unsigned short f32_to_bf16_rne(float f) {
    unsigned int u = __float_as_uint(f);
    u += 0x7FFFu + ((u >> 16) & 1u);
    return (unsigned short)(u >> 16);
}
__device__ inline unsigned pack2(float a, float b) {
    return (unsigned)f32_to_bf16_rne(a) | ((unsigned)f32_to_bf16_rne(b) << 16);
}

__global__ __launch_bounds__(512, 1) void nufft_mfma_kernel(
    const float* __restrict__ imgR,
    const float* __restrict__ imgI,
    const float* __restrict__ trj,
    float* __restrict__ out)
{
    // whole-image slab for 2 coils: [coil2][RI][128 rows * 256 B], swizzled
    __shared__ __align__(16) unsigned short slab[2][2][128 * 128];

    const int tid = threadIdx.x;
    const int bid = blockIdx.x;
    const int cg  = bid >> 7;          // coil pair: 0..3 -> coils 2cg,2cg+1
    const int kg0 = (bid & 127) * KB;  // base k of this block
    const int c0  = cg * 2;

    const int wave = tid >> 6;      // 0..7
    const int lane = tid & 63;
    const int l15  = lane & 15;
    const int lg   = lane >> 4;     // 0..3
    const int c2   = wave & 1;      // coil within pair
    const int kq   = wave >> 1;     // k-quarter (16 k's)
    const int c    = c0 + c2;       // output coil

    // ---- staging assignment: thread = (rowgrp 0..15, seg 0..31) ----
    const int rowgrp = tid >> 5;
    const int seg    = tid & 31;

    // ---- one-shot staging: 8 chunks, 2-deep disjoint-register pipeline ----
    {
        float4 L0[4], L1[4];
        const float* bR0 = imgR + (c0 * NX) * NY + seg * 4;
        const float* bI0 = imgI + (c0 * NX) * NY + seg * 4;
        const float* bR1 = imgR + ((c0 + 1) * NX) * NY + seg * 4;
        const float* bI1 = imgI + ((c0 + 1) * NX) * NY + seg * 4;

        {   // chunk 0
            const int row = rowgrp;
            L0[0] = *(const float4*)(bR0 + row * NY);
            L0[1] = *(const float4*)(bI0 + row * NY);
            L0[2] = *(const float4*)(bR1 + row * NY);
            L0[3] = *(const float4*)(bI1 + row * NY);
        }
#pragma unroll
        for (int i = 0; i < 8; ++i) {
            float4* cu = (i & 1) ? L1 : L0;
            float4* nx = (i & 1) ? L0 : L1;
            if (i < 7) {
                const int row = rowgrp + 16 * (i + 1);
                nx[0] = *(const float4*)(bR0 + row * NY);
                nx[1] = *(const float4*)(bI0 + row * NY);
                nx[2] = *(const float4*)(bR1 + row * NY);
                nx[3] = *(const float4*)(bI1 + row * NY);
            }
            const int row = rowgrp + 16 * i;
            const int off = row * 256 + ((seg * 8) ^ ((row & 15) << 4));
            uint2 v;
            v.x = pack2(cu[0].x, cu[0].y); v.y = pack2(cu[0].z, cu[0].w);
            *(uint2*)((char*)&slab[0][0][0] + off) = v;
            v.x = pack2(cu[1].x, cu[1].y); v.y = pack2(cu[1].z, cu[1].w);
            *(uint2*)((char*)&slab[0][1][0] + off) = v;
            v.x = pack2(cu[2].x, cu[2].y); v.y = pack2(cu[2].z, cu[2].w);
            *(uint2*)((char*)&slab[1][0][0] + off) = v;
            v.x = pack2(cu[3].x, cu[3].y); v.y = pack2(cu[3].z, cu[3].w);
            *(uint2*)((char*)&slab[1][1][0] + off) = v;
        }
    }

    // ---- Ey A-fragments in registers via phase recurrence (overlaps loads) ----
    // A layout (16x16x32): row = lane&15 -> k = kq*16+l15; k slot y = lg*8+idx
    // (+32 per ys). One ky per lane; walk y by cmul with exp(-2πi ky/128).
    bf16x8 aR[4], aI[4];
    {
        const float ky = trj[(kg0 + kq * 16 + l15) * 2 + 1];
        float u = -ky * (1.0f / 128.0f); u -= floorf(u);
        float s1i, s1r; __sincosf(6.283185307179586f * u, &s1i, &s1r);
#pragma unroll
        for (int ys = 0; ys < 4; ++ys) {
            const int y0 = ys * 32 + lg * 8;
            float t = -ky * (float)(y0 - 64) * (1.0f / 128.0f); t -= floorf(t);
            float ci_, cr_; __sincosf(6.283185307179586f * t, &ci_, &cr_);
#pragma unroll
            for (int m = 0; m < 8; ++m) {
                aR[ys][m] = (short)f32_to_bf16_rne(cr_);
                aI[ys][m] = (short)f32_to_bf16_rne(ci_);
                const float nr = cr_ * s1r - ci_ * s1i;
                ci_ = cr_ * s1i + ci_ * s1r;
                cr_ = nr;
            }
        }
    }

    // kx preload for stage C: k = kg0 + kq*16 + lg*4 + j
    float kxv[4];
#pragma unroll
    for (int j = 0; j < 4; ++j)
        kxv[j] = trj[(kg0 + kq * 16 + lg * 4 + j) * 2 + 0];

    __syncthreads();   // the ONLY barrier: slab fully staged & visible

    // ---- barrier-free compute: 8 x-tiles of pure ds_read + MFMA + cmul ----
    const char* sbR = (const char*)&slab[c2][0][0];
    const char* sbI = (const char*)&slab[c2][1][0];

    f32x4 outRe = {0,0,0,0};
    f32x4 outIm = {0,0,0,0};

#pragma unroll
    for (int nt = 0; nt < 8; ++nt) {
        const int x    = nt * 16 + l15;
        const int rowb = x * 256;

        f32x4 P = {0,0,0,0}, Q = {0,0,0,0}, U = {0,0,0,0}, V = {0,0,0,0};
#pragma unroll
        for (int ys = 0; ys < 4; ++ys) {
            const int inb = (lg * 16 + ys * 64) ^ (l15 << 4);
            const bf16x8 bR = *(const bf16x8*)(sbR + rowb + inb);
            const bf16x8 bI = *(const bf16x8*)(sbI + rowb + inb);
            P = __builtin_amdgcn_mfma_f32_16x16x32_bf16(aR[ys], bR, P, 0, 0, 0);
            Q = __builtin_amdgcn_mfma_f32_16x16x32_bf16(aI[ys], bI, Q, 0, 0, 0);
            U = __builtin_amdgcn_mfma_f32_16x16x32_bf16(aR[ys], bI, U, 0, 0, 0);
            V = __builtin_amdgcn_mfma_f32_16x16x32_bf16(aI[ys], bR, V, 0, 0, 0);
        }

        const float rx = (float)(x - 64) * (1.0f / 128.0f);
#pragma unroll
        for (int j = 0; j < 4; ++j) {
            float t = -kxv[j] * rx; t -= floorf(t);
            float eI_, eR_; __sincosf(6.283185307179586f * t, &eI_, &eR_);
            const float TR = P[j] - Q[j];
            const float TI = U[j] + V[j];
            outRe[j] += eR_ * TR - eI_ * TI;
            outIm[j] += eR_ * TI + eI_ * TR;
        }
    }

    // ---- reduce over the 16 x-lanes; lanes with l15==0 write ----
#pragma unroll
    for (int j = 0; j < 4; ++j) {
        float r_ = outRe[j];
        float i_ = outIm[j];
#pragma unroll
        for (int m = 1; m < 16; m <<= 1) {
            r_ += __shfl_xor(r_, m, 64);
            i_ += __shfl_xor(i_, m, 64);
        }
        if (l15 == 0) {
            const int kg = kg0 + kq * 16 + lg * 4 + j;
            ((float2*)out)[c * K_TOTAL + kg] = make_float2(r_, i_);
        }
    }
}

extern "C" void kernel_launch(void* const* d_in, const int* in_sizes, int n_in,
                              void* d_out, int out_size, void* d_ws, size_t ws_size,
                              hipStream_t stream) {
    const float* imgR = (const float*)d_in[0];
    const float* imgI = (const float*)d_in[1];
    const float* trj  = (const float*)d_in[2];
    float* out = (float*)d_out;

    hipLaunchKernelGGL(nufft_mfma_kernel, dim3(512), dim3(512), 0, stream,
                       imgR, imgI, trj, out);
}